// Round 9
// baseline (326.906 us; speedup 1.0000x reference)
//
#include <hip/hip_runtime.h>
#include <hip/hip_bf16.h>
#include <stdint.h>

#define HH 96
#define WW 96
#define NCH 256
#define PH 95
#define PW 95
#define NP 9025          // PH*PW
#define DD 1024          // 4*NCH
#define FEPS 1e-8f

#define BM 256           // tile M=N
#define BK 64            // K-step
#define NT2 36           // tiles per dim
#define NPAD2 9216       // NT2*BM
#define NBLK2 1296       // NT2*NT2 (divisible by 8)
#define KT 16            // DD/BK

typedef __attribute__((ext_vector_type(8))) short bf16x8;
typedef __attribute__((ext_vector_type(4))) float f32x4;
typedef unsigned long long u64;
typedef unsigned int u32;
using bf16 = __hip_bfloat16;

// monotone float key + inverted index => u64 max == (max score, smallest idx)
__device__ __forceinline__ u64 packSI(float v, u32 idx) {
  u32 b = __float_as_uint(v);
  u32 key = (b & 0x80000000u) ? ~b : (b | 0x80000000u);
  return ((u64)key << 32) | (u64)(~idx);
}
__device__ __forceinline__ u64 umax(u64 a, u64 b) { return a > b ? a : b; }

// per-pixel channel sum of squares; also zeroes pad rows of Sn/Tn
__global__ __launch_bounds__(256) void k_q(const float* __restrict__ src,
                                           const float* __restrict__ tgt,
                                           float* __restrict__ q_s,
                                           float* __restrict__ q_t,
                                           bf16* __restrict__ Sn,
                                           bf16* __restrict__ Tn) {
  int p = blockIdx.x * 256 + threadIdx.x;  // 36*256 == 9216 exactly
  const float* img = blockIdx.y ? tgt : src;
  float acc = 0.f;
  #pragma unroll 8
  for (int c = 0; c < NCH; ++c) {
    float v = img[(size_t)c * (HH * WW) + p];
    acc = fmaf(v, v, acc);
  }
  (blockIdx.y ? q_t : q_s)[p] = acc;
  // zero pad rows NP..NPAD2 (so pad scores are exactly 0 and never win)
  const int padWords = (NPAD2 - NP) * DD / 2;  // u32 words
  u32* pw = (u32*)((blockIdx.y ? Tn : Sn) + (size_t)NP * DD);
  for (int j = p; j < padWords; j += 36 * 256) pw[j] = 0u;
}

// per-patch squared norm = 4-point sum of q
__global__ __launch_bounds__(256) void k_sq(const float* __restrict__ q_s,
                                            const float* __restrict__ q_t,
                                            float* __restrict__ sq_s,
                                            float* __restrict__ sq_t) {
  int n = blockIdx.x * 256 + threadIdx.x;
  if (n >= NP) return;
  int y = n / PW, x = n - y * PW;
  int b = y * WW + x;
  sq_s[n] = q_s[b] + q_s[b + 1] + q_s[b + WW] + q_s[b + WW + 1];
  sq_t[n] = q_t[b] + q_t[b + 1] + q_t[b + WW] + q_t[b + WW + 1];
}

// normalized bf16 patch matrix [NPAD2][DD], written via LDS transpose
// z = 0: (src, sq_s) -> Sn ; z = 1: (tgt, sq_t) -> Tn
__global__ __launch_bounds__(128) void k_norm(const float* __restrict__ src,
                                              const float* __restrict__ tgt,
                                              const float* __restrict__ sq_s,
                                              const float* __restrict__ sq_t,
                                              bf16* __restrict__ Sn,
                                              bf16* __restrict__ Tn) {
  __shared__ float tile[64 * 129];
  __shared__ float rn[PW];
  const float* img = blockIdx.z ? tgt : src;
  const float* sq = blockIdx.z ? sq_t : sq_s;
  bf16* out = blockIdx.z ? Tn : Sn;
  int y = blockIdx.y;
  int d0 = blockIdx.x * 64;     // 16 chunks of 64 d's
  int k = d0 >> 8;              // which 2x2 shift
  int c0 = d0 & 255;
  int iy = k >> 1, jx = k & 1;
  int t = threadIdx.x;
  if (t < PW) rn[t] = 1.f / (sqrtf(sq[y * PW + t]) + FEPS);
  int x = t;
  const float* base = img + (size_t)(y + iy) * WW + jx;
  #pragma unroll 4
  for (int dl = 0; dl < 64; ++dl) {
    int c = c0 + dl;
    float v = (x < PW) ? base[(size_t)c * (HH * WW) + x] : 0.f;
    tile[dl * 129 + x] = v;
  }
  __syncthreads();
  int dl = t & 63, xh = t >> 6;
  for (int xl = xh; xl < PW; xl += 2) {
    out[(size_t)(y * PW + xl) * DD + d0 + dl] =
        __float2bfloat16(tile[dl * 129 + xl] * rn[xl]);
  }
}

// ---- inline-asm helpers for the GEMM schedule ----
#define DSR(dst, base, IMMSTR) \
  asm volatile("ds_read_b128 %0, %1 offset:" IMMSTR : "=v"(dst) : "v"(base))
#define WAITL(NSTR) asm volatile("s_waitcnt lgkmcnt(" NSTR ")" ::: "memory")
#define SB0 __builtin_amdgcn_sched_barrier(0)

// 256x256-tile bf16 MFMA GEMM (scores = Tn * Sn^T).
// BARRIER-FREE K-tile body: per tile only {barrier A | stage next tile |
// counted vmcnt(8) | barrier B}, then all 24 ds_reads + 64 MFMA run as one
// staggered per-wave stream (lgkmcnt(7..0), 2-MFMA granularity) with waves
// free to skew across the whole tile -> DS pipe and MFMA pipe overlap across
// waves. T2 both-sides XOR swizzle; T5 setprio. Fused argmax -> partials.
// LDS: [dbuf 2][piece: A0,A1,B0,B1][128 rows][64 bf16] = 128 KiB.
__global__ __launch_bounds__(512, 2) void k_gemm(const bf16* __restrict__ Tn,
                                                 const bf16* __restrict__ Sn,
                                                 u64* __restrict__ rowPart,
                                                 u64* __restrict__ colPart) {
  __shared__ __align__(16) char ldsc[131072];  // 128 KiB

  int bid = blockIdx.x;
  // XCD swizzle: NBLK2 % 8 == 0 -> simple chunked form
  int swz = (bid & 7) * (NBLK2 / 8) + (bid >> 3);
  int rt = swz / NT2, ct = swz % NT2;
  int tileR = rt * BM, tileC = ct * BM;

  int tid = threadIdx.x;
  int lane = tid & 63, wid = tid >> 6;
  int wm = wid >> 2, wn = wid & 3;       // 2 x 4 wave grid; per-wave out 128x64
  int lcol = lane & 15, lrow = lane >> 4;

  const bf16* gA = Tn + (size_t)tileR * DD;
  const bf16* gB = Sn + (size_t)tileC * DD;

  f32x4 acc[8][4] = {};

  // precomputed LDS byte bases: swizzle term ((ks*4+lrow)^(lcol&7))*16 is
  // independent of the fragment index, so each read = base + imm.
  u32 lbase = (u32)(uintptr_t)ldsc;
  u32 comm = (u32)lcol * 128u;
  u32 aoff[2][2], boff[2][2];
  #pragma unroll
  for (int db2 = 0; db2 < 2; ++db2)
    #pragma unroll
    for (int ks2 = 0; ks2 < 2; ++ks2) {
      u32 term = ((u32)((ks2 * 4 + lrow) ^ (lcol & 7))) << 4;
      aoff[db2][ks2] = lbase + (u32)(db2 * 4 + wm) * 16384u + comm + term;
      boff[db2][ks2] = lbase + (u32)(db2 * 4 + 2 + (wn >> 1)) * 16384u +
                       (u32)(wn & 1) * 8192u + comm + term;
    }

  // stage one half-tile (piece pc: 0=A0,1=A1,2=B0,3=B1) of K-tile t, dbuf db.
  // linear LDS dest + inverse-swizzled global source column (involution).
  auto STAGE1 = [&](int db, int t, int pc) {
    int M = pc >> 1, h = pc & 1;
    int k0 = t * BK;
    const bf16* gsrc = M ? gB : gA;
    #pragma unroll
    for (int q2 = 0; q2 < 2; ++q2) {
      int ch = q2 * 512 + tid;           // 16-B chunk within 16KB piece
      int r = ch >> 3, s = ch & 7;
      int ldofs = (db * 4 + pc) * 16384 + ch * 16;
      const bf16* g = gsrc + (size_t)(h * 128 + r) * DD + k0 + ((s ^ (r & 7)) << 3);
      __builtin_amdgcn_global_load_lds(
          (const __attribute__((address_space(1))) void*)g,
          (__attribute__((address_space(3))) void*)(ldsc + ldofs), 16, 0, 0);
    }
  };

  bf16x8 a[8], b[2];
#define MMH(m) do { \
    acc[m][0] = __builtin_amdgcn_mfma_f32_16x16x32_bf16(a[m], b[0], acc[m][0], 0, 0, 0); \
    acc[m][1] = __builtin_amdgcn_mfma_f32_16x16x32_bf16(a[m], b[1], acc[m][1], 0, 0, 0); \
  } while (0)
#define MML(m) do { \
    acc[m][2] = __builtin_amdgcn_mfma_f32_16x16x32_bf16(a[m], b[0], acc[m][2], 0, 0, 0); \
    acc[m][3] = __builtin_amdgcn_mfma_f32_16x16x32_bf16(a[m], b[1], acc[m][3], 0, 0, 0); \
  } while (0)

  // one BK=32 k-slice: 12 ordered reads, staggered waits, 32 MFMA, no barrier
#define KSRUN(PD, KS) do { \
    DSR(b[0], boff[PD][KS], "0");     DSR(b[1], boff[PD][KS], "2048"); \
    DSR(a[0], aoff[PD][KS], "0");     DSR(a[1], aoff[PD][KS], "2048"); \
    DSR(a[2], aoff[PD][KS], "4096");  DSR(a[3], aoff[PD][KS], "6144"); \
    DSR(a[4], aoff[PD][KS], "8192");  DSR(a[5], aoff[PD][KS], "10240"); \
    DSR(a[6], aoff[PD][KS], "12288"); DSR(a[7], aoff[PD][KS], "14336"); \
    __builtin_amdgcn_s_setprio(1); \
    WAITL("7"); SB0; MMH(0); \
    WAITL("6"); SB0; MMH(1); \
    WAITL("5"); SB0; MMH(2); \
    WAITL("4"); SB0; MMH(3); \
    WAITL("3"); SB0; MMH(4); \
    WAITL("2"); SB0; MMH(5); \
    WAITL("1"); SB0; MMH(6); \
    WAITL("0"); SB0; MMH(7); \
    __builtin_amdgcn_s_setprio(0); \
    DSR(b[0], boff[PD][KS], "4096");  DSR(b[1], boff[PD][KS], "6144"); \
    __builtin_amdgcn_s_setprio(1); \
    WAITL("0"); SB0; \
    MML(0); MML(1); MML(2); MML(3); MML(4); MML(5); MML(6); MML(7); \
    __builtin_amdgcn_s_setprio(0); \
  } while (0)

  // ---- prologue: stage tile 0 into dbuf 0
  #pragma unroll
  for (int pc = 0; pc < 4; ++pc) STAGE1(0, 0, pc);

  for (int it = 0; it < KT / 2; ++it) {
    int t1 = 2 * it + 1, t2 = 2 * it + 2;
    // ---- tile 2it (dbuf 0)
    __builtin_amdgcn_s_barrier();        // A: all waves done reading dbuf 1
    #pragma unroll
    for (int pc = 0; pc < 4; ++pc) STAGE1(1, t1, pc);   // t1 <= 15 always
    asm volatile("s_waitcnt vmcnt(8)" ::: "memory");    // tile 2it landed
    __builtin_amdgcn_s_barrier();        // B: everyone's loads visible
    KSRUN(0, 0);
    KSRUN(0, 1);
    // ---- tile 2it+1 (dbuf 1)
    __builtin_amdgcn_s_barrier();        // A: all waves done reading dbuf 0
    if (t2 < KT) {
      #pragma unroll
      for (int pc = 0; pc < 4; ++pc) STAGE1(0, t2, pc);
      asm volatile("s_waitcnt vmcnt(8)" ::: "memory");
    } else {
      asm volatile("s_waitcnt vmcnt(0)" ::: "memory");  // tail drain (once)
    }
    __builtin_amdgcn_s_barrier();        // B
    KSRUN(1, 0);
    KSRUN(1, 1);
  }

  // ---- epilogue: bidirectional argmax to per-tile partials, no atomics ----
  __syncthreads();                  // full drain; LDS now reusable
  u64* rowLds = (u64*)ldsc;           // [4 wn][256 rows]  8KB
  u64* colLds = (u64*)(ldsc + 8192);  // [2 wm][256 cols]  4KB

  // row best: per target row, over this wave's 64 source cols
  #pragma unroll
  for (int m = 0; m < 8; ++m) {
    #pragma unroll
    for (int j = 0; j < 4; ++j) {
      u64 best = 0ull;
      #pragma unroll
      for (int n = 0; n < 4; ++n)
        best = umax(best, packSI(acc[m][n][j], (u32)(tileC + wn * 64 + n * 16 + lcol)));
      #pragma unroll
      for (int s = 1; s < 16; s <<= 1)
        best = umax(best, (u64)__shfl_xor(best, s, 64));
      if (lcol == 0)
        rowLds[wn * 256 + wm * 128 + m * 16 + lrow * 4 + j] = best;
    }
  }
  // col best: per source col, over this wave's 128 target rows
  #pragma unroll
  for (int n = 0; n < 4; ++n) {
    u64 best = 0ull;
    #pragma unroll
    for (int m = 0; m < 8; ++m)
      #pragma unroll
      for (int j = 0; j < 4; ++j)
        best = umax(best, packSI(acc[m][n][j], (u32)(tileR + wm * 128 + m * 16 + lrow * 4 + j)));
    #pragma unroll
    for (int s = 16; s < 64; s <<= 1)
      best = umax(best, (u64)__shfl_xor(best, s, 64));
    if (lrow == 0)
      colLds[wm * 256 + wn * 64 + n * 16 + lcol] = best;
  }
  __syncthreads();
  if (tid < 256) {
    u64 b2 = rowLds[tid];
    b2 = umax(b2, rowLds[256 + tid]);
    b2 = umax(b2, rowLds[512 + tid]);
    b2 = umax(b2, rowLds[768 + tid]);
    rowPart[(size_t)ct * NPAD2 + tileR + tid] = b2;
  } else {
    int c = tid - 256;
    u64 b2 = umax(colLds[c], colLds[256 + c]);
    colPart[(size_t)rt * NPAD2 + tileC + c] = b2;
  }
#undef KSRUN
#undef MMH
#undef MML
}

// per-n max over 36 tile-partials + analytic loss contributions -> per-block sums
__global__ __launch_bounds__(256) void k_redloss(const u64* __restrict__ rowPart,
                                                 const u64* __restrict__ colPart,
                                                 const float* __restrict__ sq_s,
                                                 const float* __restrict__ sq_t,
                                                 float* __restrict__ part) {
  __shared__ float r0[256], r1[256];
  int t = threadIdx.x;
  int n = blockIdx.x * 256 + t;   // grid 36 -> 9216
  float lt = 0.f, ls = 0.f;
  u64 r = 0ull, c = 0ull;
  for (int i = 0; i < NT2; ++i) {
    u64 x = rowPart[(size_t)i * NPAD2 + n]; if (x > r) r = x;
    u64 y = colPart[(size_t)i * NPAD2 + n]; if (y > c) c = y;
  }
  if (n < NP) {
    {
      u32 key = (u32)(r >> 32);
      u32 bb = (key & 0x80000000u) ? (key ^ 0x80000000u) : ~key;
      float sc = __uint_as_float(bb);
      u32 m = ~((u32)r);
      float a = sq_t[n], cc = sq_s[m];
      lt = a + cc - 2.f * sc * (sqrtf(a) + FEPS) * (sqrtf(cc) + FEPS);
    }
    {
      u32 key = (u32)(c >> 32);
      u32 bb = (key & 0x80000000u) ? (key ^ 0x80000000u) : ~key;
      float sc = __uint_as_float(bb);
      u32 m = ~((u32)c);
      float a = sq_s[n], cc = sq_t[m];
      ls = a + cc - 2.f * sc * (sqrtf(a) + FEPS) * (sqrtf(cc) + FEPS);
    }
  }
  r0[t] = lt; r1[t] = ls;
  __syncthreads();
  for (int s = 128; s > 0; s >>= 1) {
    if (t < s) { r0[t] += r0[t + s]; r1[t] += r1[t + s]; }
    __syncthreads();
  }
  if (t == 0) { part[blockIdx.x * 2] = r0[0]; part[blockIdx.x * 2 + 1] = r1[0]; }
}

// deterministic final sum of the 36 per-block partials
__global__ __launch_bounds__(64) void k_fin(const float* __restrict__ part,
                                            float* __restrict__ out) {
  int l = threadIdx.x;
  float lt = (l < NT2) ? part[l * 2] : 0.f;
  float ls = (l < NT2) ? part[l * 2 + 1] : 0.f;
  #pragma unroll
  for (int s = 1; s < 64; s <<= 1) {
    lt += __shfl_xor(lt, s, 64);
    ls += __shfl_xor(ls, s, 64);
  }
  if (l == 0) {
    const float scale = 0.5f / ((float)NP * (float)DD);
    out[0] = lt * scale;   // loss_target
    out[1] = ls * scale;   // loss_source
  }
}

extern "C" void kernel_launch(void* const* d_in, const int* in_sizes, int n_in,
                              void* d_out, int out_size, void* d_ws, size_t ws_size,
                              hipStream_t stream) {
  const float* src = (const float*)d_in[0];
  const float* tgt = (const float*)d_in[1];
  float* out = (float*)d_out;
  char* ws = (char*)d_ws;
  size_t o = 0;
  bf16* Sn = (bf16*)(ws + o); o += (size_t)NPAD2 * DD * 2;
  bf16* Tn = (bf16*)(ws + o); o += (size_t)NPAD2 * DD * 2;
  float* sq_s = (float*)(ws + o); o += (size_t)NPAD2 * 4;
  float* sq_t = (float*)(ws + o); o += (size_t)NPAD2 * 4;
  float* q_s = (float*)(ws + o); o += (size_t)HH * WW * 4;
  float* q_t = (float*)(ws + o); o += (size_t)HH * WW * 4;
  u64* rowPart = (u64*)(ws + o); o += (size_t)NT2 * NPAD2 * 8;
  u64* colPart = (u64*)(ws + o); o += (size_t)NT2 * NPAD2 * 8;
  float* part = (float*)(ws + o); o += 1024;
  if (ws_size < o) return;  // ~43 MiB needed

  k_q<<<dim3(36, 2), 256, 0, stream>>>(src, tgt, q_s, q_t, Sn, Tn);
  k_sq<<<36, 256, 0, stream>>>(q_s, q_t, sq_s, sq_t);
  k_norm<<<dim3(16, PH, 2), 128, 0, stream>>>(src, tgt, sq_s, sq_t, Sn, Tn);
  k_gemm<<<NBLK2, 512, 0, stream>>>(Tn, Sn, rowPart, colPart);
  k_redloss<<<36, 256, 0, stream>>>(rowPart, colPart, sq_s, sq_t, part);
  k_fin<<<1, 64, 0, stream>>>(part, out);
}

// Round 10
// 242.281 us; speedup vs baseline: 1.3493x; 1.3493x over previous
//
#include <hip/hip_runtime.h>
#include <hip/hip_bf16.h>
#include <stdint.h>

#define HH 96
#define WW 96
#define NCH 256
#define PH 95
#define PW 95
#define NP 9025          // PH*PW
#define DD 1024          // 4*NCH (bytes per row in i8)
#define FEPS 1e-8f

#define BMT 128          // target rows per block
#define BNS 256          // source cols per block
#define NTM 72           // row tiles (9216/128)
#define NTN 36           // col tiles (9216/256)
#define NPAD2 9216
#define NBLK3 2592       // NTM*NTN (divisible by 8)
#define KT 16            // DD/64
#define QSCL 508.0f
#define QS2 (1.0f / (508.0f * 508.0f))

typedef __attribute__((ext_vector_type(4))) int i32x4;
typedef unsigned long long u64;
typedef unsigned int u32;
using bf16 = __hip_bfloat16;

// monotone float key + inverted index => u64 max == (max score, smallest idx)
__device__ __forceinline__ u64 packSI(float v, u32 idx) {
  u32 b = __float_as_uint(v);
  u32 key = (b & 0x80000000u) ? ~b : (b | 0x80000000u);
  return ((u64)key << 32) | (u64)(~idx);
}
__device__ __forceinline__ u64 umax(u64 a, u64 b) { return a > b ? a : b; }

// per-pixel channel sum of squares; also zeroes pad rows of Sq/Tq (i8)
__global__ __launch_bounds__(256) void k_q(const float* __restrict__ src,
                                           const float* __restrict__ tgt,
                                           float* __restrict__ q_s,
                                           float* __restrict__ q_t,
                                           int8_t* __restrict__ Sq,
                                           int8_t* __restrict__ Tq) {
  int p = blockIdx.x * 256 + threadIdx.x;  // 36*256 == 9216 exactly
  const float* img = blockIdx.y ? tgt : src;
  float acc = 0.f;
  #pragma unroll 8
  for (int c = 0; c < NCH; ++c) {
    float v = img[(size_t)c * (HH * WW) + p];
    acc = fmaf(v, v, acc);
  }
  (blockIdx.y ? q_t : q_s)[p] = acc;
  // zero pad rows NP..NPAD2 (pad dot = 0, cos = 0, never wins)
  const int padWords = (NPAD2 - NP) * DD / 4;  // u32 words
  u32* pw = (u32*)((blockIdx.y ? Tq : Sq) + (size_t)NP * DD);
  for (int j = p; j < padWords; j += 36 * 256) pw[j] = 0u;
}

// per-patch squared norm = 4-point sum of q
__global__ __launch_bounds__(256) void k_sq(const float* __restrict__ q_s,
                                            const float* __restrict__ q_t,
                                            float* __restrict__ sq_s,
                                            float* __restrict__ sq_t) {
  int n = blockIdx.x * 256 + threadIdx.x;
  if (n >= NP) return;
  int y = n / PW, x = n - y * PW;
  int b = y * WW + x;
  sq_s[n] = q_s[b] + q_s[b + 1] + q_s[b + WW] + q_s[b + WW + 1];
  sq_t[n] = q_t[b] + q_t[b + 1] + q_t[b + WW] + q_t[b + WW + 1];
}

// normalized, globally-scaled i8 patch matrix [NPAD2][DD] via LDS transpose
// z = 0: (src, sq_s) -> Sq ; z = 1: (tgt, sq_t) -> Tq
__global__ __launch_bounds__(128) void k_norm(const float* __restrict__ src,
                                              const float* __restrict__ tgt,
                                              const float* __restrict__ sq_s,
                                              const float* __restrict__ sq_t,
                                              int8_t* __restrict__ Sq,
                                              int8_t* __restrict__ Tq) {
  __shared__ float tile[64 * 129];
  __shared__ float rn[PW];
  const float* img = blockIdx.z ? tgt : src;
  const float* sq = blockIdx.z ? sq_t : sq_s;
  int8_t* out = blockIdx.z ? Tq : Sq;
  int y = blockIdx.y;
  int d0 = blockIdx.x * 64;     // 16 chunks of 64 d's
  int k = d0 >> 8;              // which 2x2 shift
  int c0 = d0 & 255;
  int iy = k >> 1, jx = k & 1;
  int t = threadIdx.x;
  if (t < PW) rn[t] = QSCL / (sqrtf(sq[y * PW + t]) + FEPS);
  int x = t;
  const float* base = img + (size_t)(y + iy) * WW + jx;
  #pragma unroll 4
  for (int dl = 0; dl < 64; ++dl) {
    int c = c0 + dl;
    float v = (x < PW) ? base[(size_t)c * (HH * WW) + x] : 0.f;
    tile[dl * 129 + x] = v;
  }
  __syncthreads();
  int dl = t & 63, xh = t >> 6;
  for (int xl = xh; xl < PW; xl += 2) {
    float qv = tile[dl * 129 + xl] * rn[xl];
    qv = fminf(fmaxf(qv, -127.f), 127.f);
    out[(size_t)(y * PW + xl) * DD + d0 + dl] = (int8_t)(int)rintf(qv);
  }
}

// ---- inline-asm helpers ----
#define DSR(dst, base, IMMSTR) \
  asm volatile("ds_read_b128 %0, %1 offset:" IMMSTR : "=v"(dst) : "v"(base))
#define WAITL(NSTR) asm volatile("s_waitcnt lgkmcnt(" NSTR ")" ::: "memory")
#define SB0 __builtin_amdgcn_sched_barrier(0)

// 128x256-tile i8 MFMA GEMM (cos*QS2^-1 = Tq . Sq^T, i32 exact dot).
// mfma_i32_16x16x64_i8; per K-tile(64B): 8 b128 reads + 16 MFMA per wave,
// R8-style stagger; 2 barriers/tile; counted vmcnt(3). T2 4-slot XOR swizzle
// (both-sides involution). 48 KiB LDS + <=128 VGPR -> 2 blocks/CU.
// Fused bidirectional argmax -> per-tile partials (no atomics).
// LDS: [dbuf 2][A 128x64B | B 256x64B] = 2 x 24 KiB.
__global__ __launch_bounds__(512, 4) void k_gemm(const int8_t* __restrict__ Tq,
                                                 const int8_t* __restrict__ Sq,
                                                 u64* __restrict__ rowPart,
                                                 u64* __restrict__ colPart) {
  __shared__ __align__(16) char ldsc[49152];

  int bid = blockIdx.x;
  // XCD swizzle: NBLK3 % 8 == 0 -> chunked; consecutive swz share the A panel
  int swz = (bid & 7) * (NBLK3 / 8) + (bid >> 3);
  int rt = swz / NTN, ct = swz % NTN;
  int tileR = rt * BMT, tileC = ct * BNS;

  int tid = threadIdx.x;
  int lane = tid & 63, wid = tid >> 6;
  int wm = wid >> 2, wn = wid & 3;       // 2 x 4 wave grid; per-wave out 64x64
  int lcol = lane & 15, lrow = lane >> 4;

  const int8_t* gA = Tq + (size_t)tileR * DD;
  const int8_t* gB = Sq + (size_t)tileC * DD;

  i32x4 acc[4][4] = {};

  // LDS read bases: swizzle term (lrow^(lcol&3))*16 is fragment-independent
  u32 lbase = (u32)(uintptr_t)ldsc;
  u32 swz16 = ((u32)(lrow ^ (lcol & 3))) << 4;
  u32 aoff0 = lbase + (u32)(wm * 64 + lcol) * 64u + swz16;
  u32 boff0 = lbase + 8192u + (u32)(wn * 64 + lcol) * 64u + swz16;
  u32 aoff1 = aoff0 + 24576u, boff1 = boff0 + 24576u;

  // stage K-tile t into dbuf db: linear LDS dest + inverse-swizzled global col
  auto STAGE = [&](int db, int t) {
    int k0 = t * 64;
    {
      int r = tid >> 2, s = tid & 3;     // A: 128x64B, 1 chunk/thread
      const int8_t* g = gA + (size_t)r * DD + k0 + ((s ^ (r & 3)) << 4);
      __builtin_amdgcn_global_load_lds(
          (const __attribute__((address_space(1))) void*)g,
          (__attribute__((address_space(3))) void*)(ldsc + db * 24576 + tid * 16),
          16, 0, 0);
    }
    #pragma unroll
    for (int q2 = 0; q2 < 2; ++q2) {     // B: 256x64B, 2 chunks/thread
      int ch = q2 * 512 + tid;
      int r = ch >> 2, s = ch & 3;
      const int8_t* g = gB + (size_t)r * DD + k0 + ((s ^ (r & 3)) << 4);
      __builtin_amdgcn_global_load_lds(
          (const __attribute__((address_space(1))) void*)g,
          (__attribute__((address_space(3))) void*)(ldsc + db * 24576 + 8192 + ch * 16),
          16, 0, 0);
    }
  };

  i32x4 a[4], b[4];
#define MM(m) do { \
    acc[m][0] = __builtin_amdgcn_mfma_i32_16x16x64_i8(a[m], b[0], acc[m][0], 0, 0, 0); \
    acc[m][1] = __builtin_amdgcn_mfma_i32_16x16x64_i8(a[m], b[1], acc[m][1], 0, 0, 0); \
    acc[m][2] = __builtin_amdgcn_mfma_i32_16x16x64_i8(a[m], b[2], acc[m][2], 0, 0, 0); \
    acc[m][3] = __builtin_amdgcn_mfma_i32_16x16x64_i8(a[m], b[3], acc[m][3], 0, 0, 0); \
  } while (0)

#define KSRUN(AOFF, BOFF) do { \
    DSR(a[0], AOFF, "0"); \
    DSR(b[0], BOFF, "0");    DSR(b[1], BOFF, "1024"); \
    DSR(b[2], BOFF, "2048"); DSR(b[3], BOFF, "3072"); \
    DSR(a[1], AOFF, "1024"); DSR(a[2], AOFF, "2048"); DSR(a[3], AOFF, "3072"); \
    __builtin_amdgcn_s_setprio(1); \
    WAITL("3"); SB0; MM(0); \
    WAITL("2"); SB0; MM(1); \
    WAITL("1"); SB0; MM(2); \
    WAITL("0"); SB0; MM(3); \
    __builtin_amdgcn_s_setprio(0); \
  } while (0)

  STAGE(0, 0);
  for (int it = 0; it < KT / 2; ++it) {
    int t1 = 2 * it + 1, t2 = 2 * it + 2;
    __builtin_amdgcn_s_barrier();        // reads of tile 2it-1 retired
    STAGE(1, t1);                        // t1 <= 15 always
    asm volatile("s_waitcnt vmcnt(3)" ::: "memory");   // tile 2it landed
    __builtin_amdgcn_s_barrier();        // visible to all waves
    KSRUN(aoff0, boff0);
    __builtin_amdgcn_s_barrier();        // reads of tile 2it retired
    if (t2 < KT) {
      STAGE(0, t2);
      asm volatile("s_waitcnt vmcnt(3)" ::: "memory");
    } else {
      asm volatile("s_waitcnt vmcnt(0)" ::: "memory");
    }
    __builtin_amdgcn_s_barrier();
    KSRUN(aoff1, boff1);
  }

  // ---- epilogue: bidirectional argmax to per-tile partials, no atomics ----
  __syncthreads();                  // full drain; LDS now reusable
  u64* rowLds = (u64*)ldsc;           // [4 wn][128 rows]  4KB
  u64* colLds = (u64*)(ldsc + 4096);  // [2 wm][256 cols]  4KB

  // row best: per target row, over this wave's 64 source cols
  #pragma unroll
  for (int m = 0; m < 4; ++m) {
    #pragma unroll
    for (int j = 0; j < 4; ++j) {
      u64 best = 0ull;
      #pragma unroll
      for (int n = 0; n < 4; ++n) {
        float cos = (float)acc[m][n][j] * QS2;
        best = umax(best, packSI(cos, (u32)(tileC + wn * 64 + n * 16 + lcol)));
      }
      #pragma unroll
      for (int s = 1; s < 16; s <<= 1)
        best = umax(best, (u64)__shfl_xor(best, s, 64));
      if (lcol == 0)
        rowLds[wn * 128 + wm * 64 + m * 16 + lrow * 4 + j] = best;
    }
  }
  // col best: per source col, over this wave's 64 target rows
  #pragma unroll
  for (int n = 0; n < 4; ++n) {
    u64 best = 0ull;
    #pragma unroll
    for (int m = 0; m < 4; ++m)
      #pragma unroll
      for (int j = 0; j < 4; ++j) {
        float cos = (float)acc[m][n][j] * QS2;
        best = umax(best, packSI(cos, (u32)(tileR + wm * 64 + m * 16 + lrow * 4 + j)));
      }
    #pragma unroll
    for (int s = 16; s < 64; s <<= 1)
      best = umax(best, (u64)__shfl_xor(best, s, 64));
    if (lrow == 0)
      colLds[wm * 256 + wn * 64 + n * 16 + lcol] = best;
  }
  __syncthreads();
  if (tid < 128) {
    u64 b2 = rowLds[tid];
    b2 = umax(b2, rowLds[128 + tid]);
    b2 = umax(b2, rowLds[256 + tid]);
    b2 = umax(b2, rowLds[384 + tid]);
    rowPart[(size_t)ct * NPAD2 + tileR + tid] = b2;
  } else if (tid < 384) {
    int c = tid - 128;
    colPart[(size_t)rt * NPAD2 + tileC + c] = umax(colLds[c], colLds[256 + c]);
  }
#undef KSRUN
#undef MM
}

// per-n max over tile-partials (36 row / 72 col) + analytic loss -> block sums
__global__ __launch_bounds__(256) void k_redloss(const u64* __restrict__ rowPart,
                                                 const u64* __restrict__ colPart,
                                                 const float* __restrict__ sq_s,
                                                 const float* __restrict__ sq_t,
                                                 float* __restrict__ part) {
  __shared__ float r0[256], r1[256];
  int t = threadIdx.x;
  int n = blockIdx.x * 256 + t;   // grid 36 -> 9216
  float lt = 0.f, ls = 0.f;
  u64 r = 0ull, c = 0ull;
  for (int i = 0; i < NTN; ++i) {
    u64 x = rowPart[(size_t)i * NPAD2 + n]; if (x > r) r = x;
  }
  for (int i = 0; i < NTM; ++i) {
    u64 y = colPart[(size_t)i * NPAD2 + n]; if (y > c) c = y;
  }
  if (n < NP) {
    {
      u32 key = (u32)(r >> 32);
      u32 bb = (key & 0x80000000u) ? (key ^ 0x80000000u) : ~key;
      float sc = __uint_as_float(bb);
      u32 m = ~((u32)r);
      float a = sq_t[n], cc = sq_s[m];
      lt = a + cc - 2.f * sc * (sqrtf(a) + FEPS) * (sqrtf(cc) + FEPS);
    }
    {
      u32 key = (u32)(c >> 32);
      u32 bb = (key & 0x80000000u) ? (key ^ 0x80000000u) : ~key;
      float sc = __uint_as_float(bb);
      u32 m = ~((u32)c);
      float a = sq_s[n], cc = sq_t[m];
      ls = a + cc - 2.f * sc * (sqrtf(a) + FEPS) * (sqrtf(cc) + FEPS);
    }
  }
  r0[t] = lt; r1[t] = ls;
  __syncthreads();
  for (int s = 128; s > 0; s >>= 1) {
    if (t < s) { r0[t] += r0[t + s]; r1[t] += r1[t + s]; }
    __syncthreads();
  }
  if (t == 0) { part[blockIdx.x * 2] = r0[0]; part[blockIdx.x * 2 + 1] = r1[0]; }
}

// deterministic final sum of the 36 per-block partials
__global__ __launch_bounds__(64) void k_fin(const float* __restrict__ part,
                                            float* __restrict__ out) {
  int l = threadIdx.x;
  float lt = (l < 36) ? part[l * 2] : 0.f;
  float ls = (l < 36) ? part[l * 2 + 1] : 0.f;
  #pragma unroll
  for (int s = 1; s < 64; s <<= 1) {
    lt += __shfl_xor(lt, s, 64);
    ls += __shfl_xor(ls, s, 64);
  }
  if (l == 0) {
    const float scale = 0.5f / ((float)NP * (float)DD);
    out[0] = lt * scale;   // loss_target
    out[1] = ls * scale;   // loss_source
  }
}

extern "C" void kernel_launch(void* const* d_in, const int* in_sizes, int n_in,
                              void* d_out, int out_size, void* d_ws, size_t ws_size,
                              hipStream_t stream) {
  const float* src = (const float*)d_in[0];
  const float* tgt = (const float*)d_in[1];
  float* out = (float*)d_out;
  char* ws = (char*)d_ws;
  size_t o = 0;
  int8_t* Sq = (int8_t*)(ws + o); o += (size_t)NPAD2 * DD;
  int8_t* Tq = (int8_t*)(ws + o); o += (size_t)NPAD2 * DD;
  float* sq_s = (float*)(ws + o); o += (size_t)NPAD2 * 4;
  float* sq_t = (float*)(ws + o); o += (size_t)NPAD2 * 4;
  float* q_s = (float*)(ws + o); o += (size_t)HH * WW * 4;
  float* q_t = (float*)(ws + o); o += (size_t)HH * WW * 4;
  u64* rowPart = (u64*)(ws + o); o += (size_t)NTN * NPAD2 * 8;
  u64* colPart = (u64*)(ws + o); o += (size_t)NTM * NPAD2 * 8;
  float* part = (float*)(ws + o); o += 1024;
  if (ws_size < o) return;  // ~27.5 MiB needed

  k_q<<<dim3(36, 2), 256, 0, stream>>>(src, tgt, q_s, q_t, Sq, Tq);
  k_sq<<<36, 256, 0, stream>>>(q_s, q_t, sq_s, sq_t);
  k_norm<<<dim3(16, PH, 2), 128, 0, stream>>>(src, tgt, sq_s, sq_t, Sq, Tq);
  k_gemm<<<NBLK3, 512, 0, stream>>>(Tq, Sq, rowPart, colPart);
  k_redloss<<<36, 256, 0, stream>>>(rowPart, colPart, sq_s, sq_t, part);
  k_fin<<<1, 64, 0, stream>>>(part, out);
}

// Round 11
// 212.754 us; speedup vs baseline: 1.5365x; 1.1388x over previous
//
#include <hip/hip_runtime.h>
#include <hip/hip_bf16.h>
#include <stdint.h>

#define HH 96
#define WW 96
#define NCH 256
#define PH 95
#define PW 95
#define NP 9025          // PH*PW
#define DD 1024          // 4*NCH (bytes per row in i8)
#define FEPS 1e-8f

#define BMT 128          // target rows per block
#define BNS 256          // source cols per block
#define NTM 72           // row tiles (9216/128)
#define NTN 36           // col tiles (9216/256)
#define NPAD2 9216
#define NBLK3 2592       // NTM*NTN (divisible by 8)
#define KT 16            // DD/64
#define QSCL 508.0f
#define QS2 (1.0f / (508.0f * 508.0f))
#define DBIAS (1 << 19)  // dot bias (|dot| < 2^19)

typedef __attribute__((ext_vector_type(4))) int i32x4;
typedef unsigned long long u64;
typedef unsigned int u32;
using bf16 = __hip_bfloat16;

__device__ __forceinline__ u32 umx(u32 a, u32 b) { return a > b ? a : b; }
__device__ __forceinline__ u64 umax(u64 a, u64 b) { return a > b ? a : b; }

// per-pixel channel sum of squares; also zeroes pad rows of Sq/Tq (i8)
__global__ __launch_bounds__(256) void k_q(const float* __restrict__ src,
                                           const float* __restrict__ tgt,
                                           float* __restrict__ q_s,
                                           float* __restrict__ q_t,
                                           int8_t* __restrict__ Sq,
                                           int8_t* __restrict__ Tq) {
  int p = blockIdx.x * 256 + threadIdx.x;  // 36*256 == 9216 exactly
  const float* img = blockIdx.y ? tgt : src;
  float acc = 0.f;
  #pragma unroll 8
  for (int c = 0; c < NCH; ++c) {
    float v = img[(size_t)c * (HH * WW) + p];
    acc = fmaf(v, v, acc);
  }
  (blockIdx.y ? q_t : q_s)[p] = acc;
  // zero pad rows NP..NPAD2 (pad dot = 0, never wins)
  const int padWords = (NPAD2 - NP) * DD / 4;  // u32 words
  u32* pw = (u32*)((blockIdx.y ? Tq : Sq) + (size_t)NP * DD);
  for (int j = p; j < padWords; j += 36 * 256) pw[j] = 0u;
}

// per-patch squared norm = 4-point sum of q
__global__ __launch_bounds__(256) void k_sq(const float* __restrict__ q_s,
                                            const float* __restrict__ q_t,
                                            float* __restrict__ sq_s,
                                            float* __restrict__ sq_t) {
  int n = blockIdx.x * 256 + threadIdx.x;
  if (n >= NP) return;
  int y = n / PW, x = n - y * PW;
  int b = y * WW + x;
  sq_s[n] = q_s[b] + q_s[b + 1] + q_s[b + WW] + q_s[b + WW + 1];
  sq_t[n] = q_t[b] + q_t[b + 1] + q_t[b + WW] + q_t[b + WW + 1];
}

// normalized, globally-scaled i8 patch matrix [NPAD2][DD] via LDS transpose
// z = 0: (src, sq_s) -> Sq ; z = 1: (tgt, sq_t) -> Tq
__global__ __launch_bounds__(128) void k_norm(const float* __restrict__ src,
                                              const float* __restrict__ tgt,
                                              const float* __restrict__ sq_s,
                                              const float* __restrict__ sq_t,
                                              int8_t* __restrict__ Sq,
                                              int8_t* __restrict__ Tq) {
  __shared__ float tile[64 * 129];
  __shared__ float rn[PW];
  const float* img = blockIdx.z ? tgt : src;
  const float* sq = blockIdx.z ? sq_t : sq_s;
  int8_t* out = blockIdx.z ? Tq : Sq;
  int y = blockIdx.y;
  int d0 = blockIdx.x * 64;     // 16 chunks of 64 d's
  int k = d0 >> 8;              // which 2x2 shift
  int c0 = d0 & 255;
  int iy = k >> 1, jx = k & 1;
  int t = threadIdx.x;
  if (t < PW) rn[t] = QSCL / (sqrtf(sq[y * PW + t]) + FEPS);
  int x = t;
  const float* base = img + (size_t)(y + iy) * WW + jx;
  #pragma unroll 4
  for (int dl = 0; dl < 64; ++dl) {
    int c = c0 + dl;
    float v = (x < PW) ? base[(size_t)c * (HH * WW) + x] : 0.f;
    tile[dl * 129 + x] = v;
  }
  __syncthreads();
  int dl = t & 63, xh = t >> 6;
  for (int xl = xh; xl < PW; xl += 2) {
    float qv = tile[dl * 129 + xl] * rn[xl];
    qv = fminf(fmaxf(qv, -127.f), 127.f);
    out[(size_t)(y * PW + xl) * DD + d0 + dl] = (int8_t)(int)rintf(qv);
  }
}

// ---- inline-asm helpers ----
#define DSR(dst, base, IMMSTR) \
  asm volatile("ds_read_b128 %0, %1 offset:" IMMSTR : "=v"(dst) : "v"(base))
#define WAITL(NSTR) asm volatile("s_waitcnt lgkmcnt(" NSTR ")" ::: "memory")
#define SB0 __builtin_amdgcn_sched_barrier(0)

// 128x256-tile i8 MFMA GEMM (dot = Tq . Sq^T exact i32; cos = dot*QS2).
// mfma_i32_16x16x64_i8; 8 b128 + 16 MFMA per wave per 64B K-tile, R8 stagger;
// 2 barriers/tile; counted vmcnt(3). T2 swizzle f(r)=(r>>1)&3 both sides
// (2-way bank spread = free). u32-key integer argmax epilogue (monotone in
// dot; (dot+2^19)<<8 | inv_idx), b32 shuffles -> per-tile partials, no atomics.
// LDS: [dbuf 2][A 128x64B | B 256x64B] = 2 x 24 KiB; 2 blocks/CU.
__global__ __launch_bounds__(512, 4) void k_gemm(const int8_t* __restrict__ Tq,
                                                 const int8_t* __restrict__ Sq,
                                                 u64* __restrict__ rowPart,
                                                 u64* __restrict__ colPart) {
  __shared__ __align__(16) char ldsc[49152];

  int bid = blockIdx.x;
  // XCD swizzle: NBLK3 % 8 == 0 -> chunked; consecutive swz share the A panel
  int swz = (bid & 7) * (NBLK3 / 8) + (bid >> 3);
  int rt = swz / NTN, ct = swz % NTN;
  int tileR = rt * BMT, tileC = ct * BNS;

  int tid = threadIdx.x;
  int lane = tid & 63, wid = tid >> 6;
  int wm = wid >> 2, wn = wid & 3;       // 2 x 4 wave grid; per-wave out 64x64
  int lcol = lane & 15, lrow = lane >> 4;

  const int8_t* gA = Tq + (size_t)tileR * DD;
  const int8_t* gB = Sq + (size_t)tileC * DD;

  i32x4 acc[4][4] = {};

  // LDS read bases: swizzle term (lrow ^ ((lcol>>1)&3))*16, fragment-invariant
  u32 lbase = (u32)(uintptr_t)ldsc;
  u32 swz16 = ((u32)(lrow ^ ((lcol >> 1) & 3))) << 4;
  u32 aoff0 = lbase + (u32)(wm * 64 + lcol) * 64u + swz16;
  u32 boff0 = lbase + 8192u + (u32)(wn * 64 + lcol) * 64u + swz16;
  u32 aoff1 = aoff0 + 24576u, boff1 = boff0 + 24576u;

  // stage K-tile t into dbuf db: linear LDS dest + inverse-swizzled global col
  auto STAGE = [&](int db, int t) {
    int k0 = t * 64;
    {
      int r = tid >> 2, s = tid & 3;     // A: 128x64B, 1 chunk/thread
      const int8_t* g = gA + (size_t)r * DD + k0 + ((s ^ ((r >> 1) & 3)) << 4);
      __builtin_amdgcn_global_load_lds(
          (const __attribute__((address_space(1))) void*)g,
          (__attribute__((address_space(3))) void*)(ldsc + db * 24576 + tid * 16),
          16, 0, 0);
    }
    #pragma unroll
    for (int q2 = 0; q2 < 2; ++q2) {     // B: 256x64B, 2 chunks/thread
      int ch = q2 * 512 + tid;
      int r = ch >> 2, s = ch & 3;
      const int8_t* g = gB + (size_t)r * DD + k0 + ((s ^ ((r >> 1) & 3)) << 4);
      __builtin_amdgcn_global_load_lds(
          (const __attribute__((address_space(1))) void*)g,
          (__attribute__((address_space(3))) void*)(ldsc + db * 24576 + 8192 + ch * 16),
          16, 0, 0);
    }
  };

  i32x4 a[4], b[4];
#define MM(m) do { \
    acc[m][0] = __builtin_amdgcn_mfma_i32_16x16x64_i8(a[m], b[0], acc[m][0], 0, 0, 0); \
    acc[m][1] = __builtin_amdgcn_mfma_i32_16x16x64_i8(a[m], b[1], acc[m][1], 0, 0, 0); \
    acc[m][2] = __builtin_amdgcn_mfma_i32_16x16x64_i8(a[m], b[2], acc[m][2], 0, 0, 0); \
    acc[m][3] = __builtin_amdgcn_mfma_i32_16x16x64_i8(a[m], b[3], acc[m][3], 0, 0, 0); \
  } while (0)

#define KSRUN(AOFF, BOFF) do { \
    DSR(a[0], AOFF, "0"); \
    DSR(b[0], BOFF, "0");    DSR(b[1], BOFF, "1024"); \
    DSR(b[2], BOFF, "2048"); DSR(b[3], BOFF, "3072"); \
    DSR(a[1], AOFF, "1024"); DSR(a[2], AOFF, "2048"); DSR(a[3], AOFF, "3072"); \
    __builtin_amdgcn_s_setprio(1); \
    WAITL("3"); SB0; MM(0); \
    WAITL("2"); SB0; MM(1); \
    WAITL("1"); SB0; MM(2); \
    WAITL("0"); SB0; MM(3); \
    __builtin_amdgcn_s_setprio(0); \
  } while (0)

  STAGE(0, 0);
  for (int it = 0; it < KT / 2; ++it) {
    int t1 = 2 * it + 1, t2 = 2 * it + 2;
    __builtin_amdgcn_s_barrier();        // reads of tile 2it-1 retired
    STAGE(1, t1);                        // t1 <= 15 always
    asm volatile("s_waitcnt vmcnt(3)" ::: "memory");   // tile 2it landed
    __builtin_amdgcn_s_barrier();        // visible to all waves
    KSRUN(aoff0, boff0);
    __builtin_amdgcn_s_barrier();        // reads of tile 2it retired
    if (t2 < KT) {
      STAGE(0, t2);
      asm volatile("s_waitcnt vmcnt(3)" ::: "memory");
    } else {
      asm volatile("s_waitcnt vmcnt(0)" ::: "memory");
    }
    __builtin_amdgcn_s_barrier();
    KSRUN(aoff1, boff1);
  }

  // ---- epilogue: integer-key bidirectional argmax -> per-tile partials ----
  __syncthreads();                  // full drain; LDS now reusable
  u64* rowLds = (u64*)ldsc;           // [4 wn][128 rows]  4KB
  u64* colLds = (u64*)(ldsc + 4096);  // [2 wm][256 cols]  4KB

  const u32 KB = ((u32)DBIAS) << 8;   // bias<<8
  // row best: per target row (m,lrow,j), reduce over n then lcol (16 lanes)
  u32 Cr0 = KB + 255u - (u32)(wn * 64 + lcol);
  #pragma unroll
  for (int m = 0; m < 4; ++m) {
    #pragma unroll
    for (int j = 0; j < 4; ++j) {
      u32 best = umx(umx((u32)(acc[m][0][j] << 8) + Cr0,
                         (u32)(acc[m][1][j] << 8) + (Cr0 - 16u)),
                     umx((u32)(acc[m][2][j] << 8) + (Cr0 - 32u),
                         (u32)(acc[m][3][j] << 8) + (Cr0 - 48u)));
      #pragma unroll
      for (int s = 1; s < 16; s <<= 1)
        best = umx(best, (u32)__shfl_xor((int)best, s, 64));
      if (lcol == 0) {
        u32 col = (u32)tileC + 255u - (best & 255u);
        rowLds[wn * 128 + wm * 64 + m * 16 + lrow * 4 + j] =
            ((u64)(best >> 8) << 32) | (u32)~col;
      }
    }
  }
  // col best: per source col (n,lcol), reduce over (m,j) then lrow (xor 16,32)
  u32 Cc0 = KB + 127u - (u32)(wm * 64 + lrow * 4);
  #pragma unroll
  for (int n = 0; n < 4; ++n) {
    u32 best = 0u;
    #pragma unroll
    for (int m = 0; m < 4; ++m)
      #pragma unroll
      for (int j = 0; j < 4; ++j)
        best = umx(best, (u32)(acc[m][n][j] << 8) + (Cc0 - (u32)(m * 16 + j)));
    best = umx(best, (u32)__shfl_xor((int)best, 16, 64));
    best = umx(best, (u32)__shfl_xor((int)best, 32, 64));
    if (lrow == 0) {
      u32 row = (u32)tileR + 127u - (best & 255u);
      colLds[wm * 256 + wn * 64 + n * 16 + lcol] =
          ((u64)(best >> 8) << 32) | (u32)~row;
    }
  }
  __syncthreads();
  if (tid < 128) {
    u64 b2 = rowLds[tid];
    b2 = umax(b2, rowLds[128 + tid]);
    b2 = umax(b2, rowLds[256 + tid]);
    b2 = umax(b2, rowLds[384 + tid]);
    rowPart[(size_t)ct * NPAD2 + tileR + tid] = b2;
  } else if (tid < 384) {
    int c = tid - 128;
    colPart[(size_t)rt * NPAD2 + tileC + c] = umax(colLds[c], colLds[256 + c]);
  }
#undef KSRUN
#undef MM
}

// per-n max over tile-partials (36 row / 72 col) + analytic loss -> block sums
__global__ __launch_bounds__(256) void k_redloss(const u64* __restrict__ rowPart,
                                                 const u64* __restrict__ colPart,
                                                 const float* __restrict__ sq_s,
                                                 const float* __restrict__ sq_t,
                                                 float* __restrict__ part) {
  __shared__ float r0[256], r1[256];
  int t = threadIdx.x;
  int n = blockIdx.x * 256 + t;   // grid 36 -> 9216
  float lt = 0.f, ls = 0.f;
  u64 r = 0ull, c = 0ull;
  for (int i = 0; i < NTN; ++i) {
    u64 x = rowPart[(size_t)i * NPAD2 + n]; if (x > r) r = x;
  }
  for (int i = 0; i < NTM; ++i) {
    u64 y = colPart[(size_t)i * NPAD2 + n]; if (y > c) c = y;
  }
  if (n < NP) {
    {
      float sc = (float)((int)(u32)(r >> 32) - DBIAS) * QS2;
      u32 m = ~((u32)r);
      float a = sq_t[n], cc = sq_s[m];
      lt = a + cc - 2.f * sc * (sqrtf(a) + FEPS) * (sqrtf(cc) + FEPS);
    }
    {
      float sc = (float)((int)(u32)(c >> 32) - DBIAS) * QS2;
      u32 m = ~((u32)c);
      float a = sq_s[n], cc = sq_t[m];
      ls = a + cc - 2.f * sc * (sqrtf(a) + FEPS) * (sqrtf(cc) + FEPS);
    }
  }
  r0[t] = lt; r1[t] = ls;
  __syncthreads();
  for (int s = 128; s > 0; s >>= 1) {
    if (t < s) { r0[t] += r0[t + s]; r1[t] += r1[t + s]; }
    __syncthreads();
  }
  if (t == 0) { part[blockIdx.x * 2] = r0[0]; part[blockIdx.x * 2 + 1] = r1[0]; }
}

// deterministic final sum of the 36 per-block partials
__global__ __launch_bounds__(64) void k_fin(const float* __restrict__ part,
                                            float* __restrict__ out) {
  int l = threadIdx.x;
  float lt = (l < 36) ? part[l * 2] : 0.f;
  float ls = (l < 36) ? part[l * 2 + 1] : 0.f;
  #pragma unroll
  for (int s = 1; s < 64; s <<= 1) {
    lt += __shfl_xor(lt, s, 64);
    ls += __shfl_xor(ls, s, 64);
  }
  if (l == 0) {
    const float scale = 0.5f / ((float)NP * (float)DD);
    out[0] = lt * scale;   // loss_target
    out[1] = ls * scale;   // loss_source
  }
}

extern "C" void kernel_launch(void* const* d_in, const int* in_sizes, int n_in,
                              void* d_out, int out_size, void* d_ws, size_t ws_size,
                              hipStream_t stream) {
  const float* src = (const float*)d_in[0];
  const float* tgt = (const float*)d_in[1];
  float* out = (float*)d_out;
  char* ws = (char*)d_ws;
  size_t o = 0;
  int8_t* Sq = (int8_t*)(ws + o); o += (size_t)NPAD2 * DD;
  int8_t* Tq = (int8_t*)(ws + o); o += (size_t)NPAD2 * DD;
  float* sq_s = (float*)(ws + o); o += (size_t)NPAD2 * 4;
  float* sq_t = (float*)(ws + o); o += (size_t)NPAD2 * 4;
  float* q_s = (float*)(ws + o); o += (size_t)HH * WW * 4;
  float* q_t = (float*)(ws + o); o += (size_t)HH * WW * 4;
  u64* rowPart = (u64*)(ws + o); o += (size_t)NTN * NPAD2 * 8;
  u64* colPart = (u64*)(ws + o); o += (size_t)NTM * NPAD2 * 8;
  float* part = (float*)(ws + o); o += 1024;
  if (ws_size < o) return;  // ~27.5 MiB needed

  k_q<<<dim3(36, 2), 256, 0, stream>>>(src, tgt, q_s, q_t, Sq, Tq);
  k_sq<<<36, 256, 0, stream>>>(q_s, q_t, sq_s, sq_t);
  k_norm<<<dim3(16, PH, 2), 128, 0, stream>>>(src, tgt, sq_s, sq_t, Sq, Tq);
  k_gemm<<<NBLK3, 512, 0, stream>>>(Tq, Sq, rowPart, colPart);
  k_redloss<<<36, 256, 0, stream>>>(rowPart, colPart, sq_s, sq_t, part);
  k_fin<<<1, 64, 0, stream>>>(part, out);
}